// Round 10
// baseline (960.345 us; speedup 1.0000x reference)
//
#include <hip/hip_runtime.h>

#define B_SZ 16384
#define NN 7
#define HID 256
#define COMB 2048

typedef __attribute__((ext_vector_type(8))) short short8;
typedef __attribute__((ext_vector_type(4))) float floatx4;
typedef __attribute__((ext_vector_type(4))) unsigned short ushortx4;
typedef unsigned short us;

__device__ __forceinline__ float bf2f(us u) {
    union { unsigned int i; float f; } v; v.i = ((unsigned int)u) << 16; return v.f;
}
__device__ __forceinline__ us f2bf(float f) {  // RNE
    union { unsigned int i; float f; } v; v.f = f;
    return (us)((v.i + 0x7FFFu + ((v.i >> 16) & 1u)) >> 16);
}
__device__ __forceinline__ us f2bf_fast(float f) {  // round-half-up (hot path)
    union { unsigned int i; float f; } v; v.f = f;
    return (us)((v.i + 0x8000u) >> 16);
}

// LDS-only barrier (round-8: neutral vs __syncthreads, avoids the full vmcnt drain).
__device__ __forceinline__ void bar_lds() {
    asm volatile("s_waitcnt lgkmcnt(0)" ::: "memory");
    __builtin_amdgcn_s_barrier();
}

// Swizzled chunk-major offsets (chunk = 8 bf16 = 16B); verified rounds 2/4-9.
// hs: 64 rows x 256 cols -> 2048 chunks (32KB).
__device__ __forceinline__ int hoff(int r, int k8) {
    return ((r >> 3) << 8) | ((r & 7) << 5) | (k8 & 24) | ((k8 ^ r) & 7);
}
// As: 64 rows x 64 cols -> 512 chunks per buffer.
__device__ __forceinline__ int aoff(int r, int k8) {
    return ((r >> 3) << 6) | ((r & 7) << 3) | ((k8 ^ r) & 7);
}

// Pack W1 (131072), W2 (65536), wh1_w (65536), rh1_w (32768) fp32 -> contiguous bf16 dst.
__global__ __launch_bounds__(256) void pack_weights(const float* __restrict__ W1,
                                                    const float* __restrict__ W2,
                                                    const float* __restrict__ wh1,
                                                    const float* __restrict__ rh1,
                                                    us* __restrict__ dst) {
    int i = (blockIdx.x * 256 + threadIdx.x) * 4;
    if (i >= 294912) return;
    const float* src; int off;
    if (i < 131072)      { src = W1;  off = i; }
    else if (i < 196608) { src = W2;  off = i - 131072; }
    else if (i < 262144) { src = wh1; off = i - 196608; }
    else                 { src = rh1; off = i - 262144; }
    floatx4 v = *(const floatx4*)(src + off);
    ushortx4 o = {f2bf(v[0]), f2bf(v[1]), f2bf(v[2]), f2bf(v[3])};
    *(ushortx4*)(dst + i) = o;
}

// GAT attention for ONE graph by one wave, in-place in swizzled hs (round-2 verified).
template <bool WRITE_ALPHA>
__device__ __forceinline__ void attn_graph(us* hs, int r0, const float* adjs, const float* avec,
                                           float* alpha_dst, int lane) {
    const int k8 = lane >> 1, sub = (lane & 1) * 4;   // lane owns cols lane*4..lane*4+3
    float hv[NN][4];
#pragma unroll
    for (int n = 0; n < NN; ++n) {
        ushortx4 rr = *(const ushortx4*)(hs + hoff(r0 + n, k8) * 8 + sub);
        hv[n][0] = bf2f(rr[0]); hv[n][1] = bf2f(rr[1]);
        hv[n][2] = bf2f(rr[2]); hv[n][3] = bf2f(rr[3]);
    }
    floatx4 ai = *(const floatx4*)(avec + lane * 4);
    floatx4 aj = *(const floatx4*)(avec + HID + lane * 4);
    float si[NN], sj[NN];
#pragma unroll
    for (int n = 0; n < NN; ++n) {
        float pi = hv[n][0] * ai[0] + hv[n][1] * ai[1] + hv[n][2] * ai[2] + hv[n][3] * ai[3];
        float pj = hv[n][0] * aj[0] + hv[n][1] * aj[1] + hv[n][2] * aj[2] + hv[n][3] * aj[3];
#pragma unroll
        for (int off = 32; off; off >>= 1) {
            pi += __shfl_xor(pi, off);
            pj += __shfl_xor(pj, off);
        }
        si[n] = pi; sj[n] = pj;
    }
    const int j = lane & 7;
    float sjm = sj[0];
    if (j == 1) sjm = sj[1];
    if (j == 2) sjm = sj[2];
    if (j == 3) sjm = sj[3];
    if (j == 4) sjm = sj[4];
    if (j == 5) sjm = sj[5];
    if (j == 6) sjm = sj[6];
    const int jc = (j < 7) ? j : 0;
    float alpha[NN];
#pragma unroll
    for (int i = 0; i < NN; ++i) {
        float x = si[i] + sjm;
        x = (x >= 0.f) ? x : 0.2f * x;                     // leaky_relu 0.2
        bool ok = (j < 7) && (adjs[i * 7 + jc] != 0.f);    // adj mask + dummy col
        float e = ok ? x : -1e30f;
        float m = e;
        m = fmaxf(m, __shfl_xor(m, 1, 8));
        m = fmaxf(m, __shfl_xor(m, 2, 8));
        m = fmaxf(m, __shfl_xor(m, 4, 8));
        float ex = ok ? __expf(e - m) : 0.f;
        float s = ex;
        s += __shfl_xor(s, 1, 8);
        s += __shfl_xor(s, 2, 8);
        s += __shfl_xor(s, 4, 8);
        alpha[i] = (s > 0.f) ? ex * __frcp_rn(s) : 0.f;    // nan_to_num path
    }
    if (WRITE_ALPHA && lane < 7) {
#pragma unroll
        for (int i = 0; i < NN; ++i) alpha_dst[i * NN + lane] = alpha[i];
    }
#pragma unroll
    for (int i = 0; i < NN; ++i) {
        floatx4 o = (floatx4){0.f, 0.f, 0.f, 0.f};
#pragma unroll
        for (int jj = 0; jj < NN; ++jj) {
            float a = __shfl(alpha[i], jj, 8);
            o[0] += a * hv[jj][0]; o[1] += a * hv[jj][1];
            o[2] += a * hv[jj][2]; o[3] += a * hv[jj][3];
        }
        ushortx4 st = {f2bf(fmaxf(o[0], 0.f)), f2bf(fmaxf(o[1], 0.f)),
                       f2bf(fmaxf(o[2], 0.f)), f2bf(fmaxf(o[3], 0.f))};
        *(ushortx4*)(hs + hoff(r0 + i, k8) * 8 + sub) = st;   // relu
    }
}

// C-tile writeback (rows<56) into swizzled hs. col = wave*32 + ct*16 + m16.
__device__ __forceinline__ void cwrite(us* hs, floatx4 (&acc)[4][2], int wave, int quad, int m16) {
#pragma unroll
    for (int rt = 0; rt < 4; ++rt)
#pragma unroll
        for (int ct = 0; ct < 2; ++ct)
#pragma unroll
            for (int i = 0; i < 4; ++i) {
                int row = rt * 16 + quad * 4 + i;
                if (row < 56)
                    hs[hoff(row, wave * 4 + ct * 2 + (m16 >> 3)) * 8 + (m16 & 7)] =
                        f2bf(acc[rt][ct][i]);
            }
}

// ---------------- Fused kernel, templated for ablation ----------------
// FULL=true, REPS=1  : exact round-8 kernel (276us best), writes real out. Runs LAST.
// FULL=false, REPS=2 : same body with BOTH attn phases removed, 2 reps, writes scratch.
//   Purpose: measure attn share A = F - D/2 (diagnostic round; see commit note).
//   All phases stay live: finalize's global stores anchor head<-hs<-GEMM2<-hs<-GEMM1.
template <bool FULL, int REPS>
__global__ __launch_bounds__(512, 4) void fused_all_t(
    const float* __restrict__ Af, const us* __restrict__ W1b, const us* __restrict__ W2b,
    const us* __restrict__ Whb, const float* __restrict__ adj, const float* __restrict__ a1v,
    const float* __restrict__ a2v, const float* __restrict__ context,
    const float* __restrict__ wh1_b, const float* __restrict__ wh2_w,
    const float* __restrict__ wh2_b, const float* __restrict__ wh3_w,
    const float* __restrict__ wh3_b, const float* __restrict__ rh1_b,
    const float* __restrict__ rh2_w, const float* __restrict__ rh2_b,
    const float* __restrict__ base_preds, float* __restrict__ out) {
    __shared__ __attribute__((aligned(16))) us hs[16384];     // 64r x 256c swizzled chunks
    __shared__ __attribute__((aligned(16))) char ubuf[16384]; // As dbuf | red(12288B)+fin
    __shared__ float adjs[52];
    us* As = (us*)ubuf;
    float* red = (float*)ubuf;
    float* fin = red + 3072;
    const int tid = threadIdx.x;
    const int wave = tid >> 6, lane = tid & 63;
    const int quad = lane >> 4, m16 = lane & 15;
    const long gbase = (long)blockIdx.x * 8;
    if (tid < 49) adjs[tid] = adj[tid];
    // zero pad rows 56..63: padded MFMA A-rows read clean zeros
    *(ushortx4*)(hs + 14336 + tid * 4) = (ushortx4){0, 0, 0, 0};

    const int r = tid >> 3, kq8 = tid & 7;
    long rowA = gbase * 7 + r; if (rowA > 114687) rowA = 114687;   // pad-row clamp
    const float* aptr = Af + rowA * 512 + kq8 * 8;
    us* wdst = As + aoff(r, kq8) * 8;
    const int colb = wave * 32;

    for (int rep = 0; rep < REPS; ++rep) {
        floatx4 acc[4][2];
#pragma unroll
        for (int rt = 0; rt < 4; ++rt)
#pragma unroll
            for (int ct = 0; ct < 2; ++ct) acc[rt][ct] = (floatx4){0.f, 0.f, 0.f, 0.f};

        // ---- GEMM1: h1(56x256) = node_feats(56x512) @ W1^T, dbuf LDS staging ----
        floatx4 v0 = *(const floatx4*)aptr;
        floatx4 v1 = *(const floatx4*)(aptr + 4);
#pragma unroll
        for (int s = 0; s < 8; ++s) {
            short8 sv;
            sv[0] = f2bf_fast(v0[0]); sv[1] = f2bf_fast(v0[1]);
            sv[2] = f2bf_fast(v0[2]); sv[3] = f2bf_fast(v0[3]);
            sv[4] = f2bf_fast(v1[0]); sv[5] = f2bf_fast(v1[1]);
            sv[6] = f2bf_fast(v1[2]); sv[7] = f2bf_fast(v1[3]);
            if (s < 7) {   // prefetch next stage; stays in flight across bar_lds
                v0 = *(const floatx4*)(aptr + (s + 1) * 64);
                v1 = *(const floatx4*)(aptr + (s + 1) * 64 + 4);
            }
            *(short8*)(wdst + (s & 1) * 4096) = sv;
            bar_lds();                             // single LDS-only barrier/stage (dbuf)
            const us* Ab = As + (s & 1) * 4096;
            const int k0 = s * 64;
#pragma unroll
            for (int t = 0; t < 2; ++t) {
                short8 b0 = *(const short8*)(W1b + (long)(colb + m16) * 512 + k0 + t * 32 + quad * 8);
                short8 b1 = *(const short8*)(W1b + (long)(colb + 16 + m16) * 512 + k0 + t * 32 + quad * 8);
                short8 a[4];
#pragma unroll
                for (int rt = 0; rt < 4; ++rt)
                    a[rt] = *(const short8*)(Ab + aoff(rt * 16 + m16, t * 4 + quad) * 8);
#pragma unroll
                for (int rt = 0; rt < 4; ++rt) {
                    acc[rt][0] = __builtin_amdgcn_mfma_f32_16x16x32_bf16(a[rt], b0, acc[rt][0], 0, 0, 0);
                    acc[rt][1] = __builtin_amdgcn_mfma_f32_16x16x32_bf16(a[rt], b1, acc[rt][1], 0, 0, 0);
                }
            }
        }
        cwrite(hs, acc, wave, quad, m16);          // h1 pre-relu -> hs
        bar_lds();
        if constexpr (FULL) {
            attn_graph<false>(hs, wave * NN, adjs, a1v, nullptr, lane);   // x2 in place
            bar_lds();
        }

        // ---- GEMM2: h2 = x2(56x256) @ W2^T — A straight from hs, no staging ----
#pragma unroll
        for (int rt = 0; rt < 4; ++rt)
#pragma unroll
            for (int ct = 0; ct < 2; ++ct) acc[rt][ct] = (floatx4){0.f, 0.f, 0.f, 0.f};
#pragma unroll
        for (int s = 0; s < 4; ++s) {
            const int k0 = s * 64;
#pragma unroll
            for (int t = 0; t < 2; ++t) {
                short8 b0 = *(const short8*)(W2b + (long)(colb + m16) * 256 + k0 + t * 32 + quad * 8);
                short8 b1 = *(const short8*)(W2b + (long)(colb + 16 + m16) * 256 + k0 + t * 32 + quad * 8);
                short8 a[4];
#pragma unroll
                for (int rt = 0; rt < 4; ++rt)
                    a[rt] = *(const short8*)(hs + hoff(rt * 16 + m16, s * 8 + t * 4 + quad) * 8);
#pragma unroll
                for (int rt = 0; rt < 4; ++rt) {
                    acc[rt][0] = __builtin_amdgcn_mfma_f32_16x16x32_bf16(a[rt], b0, acc[rt][0], 0, 0, 0);
                    acc[rt][1] = __builtin_amdgcn_mfma_f32_16x16x32_bf16(a[rt], b1, acc[rt][1], 0, 0, 0);
                }
            }
        }
        bar_lds();                                 // all hs reads done before in-place overwrite
        cwrite(hs, acc, wave, quad, m16);          // h2 pre-relu -> hs
        bar_lds();
        if constexpr (FULL) {
            attn_graph<true>(hs, wave * NN, adjs, a2v, out + 6 * B_SZ + (gbase + wave) * 49, lane);
            bar_lds();
        }

        // ---- head GEMM: 8 graphs x 48 outs, K=2048 split over waves (wave 7 = context) ----
        floatx4 acc3[3];
#pragma unroll
        for (int ct = 0; ct < 3; ++ct) acc3[ct] = (floatx4){0.f, 0.f, 0.f, 0.f};
        const int g = m16 & 7;
#pragma unroll
        for (int s2 = 0; s2 < 8; ++s2) {
            const int kk = s2 * 32;
            short8 a;
            if (wave < 7) {
                a = *(const short8*)(hs + hoff(g * NN + wave, s2 * 4 + quad) * 8);
            } else {
                const float* cp = context + (gbase + g) * 256 + kk + quad * 8;
                floatx4 c0 = *(const floatx4*)cp;
                floatx4 c1 = *(const floatx4*)(cp + 4);
                a[0] = (short)f2bf(c0[0]); a[1] = (short)f2bf(c0[1]);
                a[2] = (short)f2bf(c0[2]); a[3] = (short)f2bf(c0[3]);
                a[4] = (short)f2bf(c1[0]); a[5] = (short)f2bf(c1[1]);
                a[6] = (short)f2bf(c1[2]); a[7] = (short)f2bf(c1[3]);
            }
#pragma unroll
            for (int ct = 0; ct < 3; ++ct) {
                short8 bh = *(const short8*)(Whb + (long)(ct * 16 + m16) * COMB + wave * 256 + kk + quad * 8);
                acc3[ct] = __builtin_amdgcn_mfma_f32_16x16x32_bf16(a, bh, acc3[ct], 0, 0, 0);
            }
        }
#pragma unroll
        for (int ct = 0; ct < 3; ++ct)
#pragma unroll
            for (int i = 0; i < 4; ++i) {
                int g2 = quad * 4 + i;             // C row = graph
                if (g2 < 8) red[wave * 384 + g2 * 48 + ct * 16 + m16] = acc3[ct][i];
            }
        bar_lds();
        if (tid < 384) {
            float ssum = 0.f;
#pragma unroll
            for (int w = 0; w < 8; ++w) ssum += red[w * 384 + tid];
            fin[tid] = ssum;
        }
        bar_lds();

        // ---- finalize: wave-parallel, 8 lanes per graph (tid<64, wave 0) ----
        const int fj = lane & 7, fg = lane >> 3;
        const long fb = gbase + fg;
        float rp = 0.f;
        float* t1s = red;            // reuse (red dead): 8*32
        float* t2s = red + 256;      // 8*16
        if (tid < 64) {
            const float* g48 = fin + fg * 48;
#pragma unroll
            for (int x = 0; x < 4; ++x) {
                int k = fj * 4 + x;
                t1s[fg * 32 + k] = fmaxf(g48[k] + wh1_b[k], 0.f);
            }
#pragma unroll
            for (int x = 0; x < 2; ++x) {
                int k = fj * 2 + x;
                float rv = tanhf(g48[32 + k] + rh1_b[k]);
                rp += rh2_w[k] * rv;
            }
        }
        bar_lds();
        if (tid < 64) {
            float s0 = wh2_b[fj * 2], s1 = wh2_b[fj * 2 + 1];
#pragma unroll
            for (int k = 0; k < 32; ++k) {
                float tv = t1s[fg * 32 + k];
                s0 += wh2_w[(fj * 2) * 32 + k] * tv;
                s1 += wh2_w[(fj * 2 + 1) * 32 + k] * tv;
            }
            t2s[fg * 16 + fj * 2] = fmaxf(s0, 0.f);
            t2s[fg * 16 + fj * 2 + 1] = fmaxf(s1, 0.f);
        }
        bar_lds();
        if (tid < 64) {
            float rw = -1e30f;
            if (fj < 5) {
                float s = wh3_b[fj];
#pragma unroll
                for (int k = 0; k < 16; ++k) s += wh3_w[fj * 16 + k] * t2s[fg * 16 + k];
                rw = s;
            }
            float m = rw;
            m = fmaxf(m, __shfl_xor(m, 1, 8));
            m = fmaxf(m, __shfl_xor(m, 2, 8));
            m = fmaxf(m, __shfl_xor(m, 4, 8));
            float e = (fj < 5) ? __expf(rw - m) : 0.f;
            float se = e;
            se += __shfl_xor(se, 1, 8);
            se += __shfl_xor(se, 2, 8);
            se += __shfl_xor(se, 4, 8);
            float inv = 1.f / se;
            float wp = 0.f;
            if (fj < 5) {
                float w = e * inv;
                out[B_SZ + fb * 5 + fj] = w;
                wp = w * base_preds[fb * 5 + fj];
            }
            wp += __shfl_xor(wp, 1, 8);
            wp += __shfl_xor(wp, 2, 8);
            wp += __shfl_xor(wp, 4, 8);
            float rs = rp;
            rs += __shfl_xor(rs, 1, 8);
            rs += __shfl_xor(rs, 2, 8);
            rs += __shfl_xor(rs, 4, 8);
            if (fj == 0) out[fb] = fmaxf(wp + (rs + rh2_b[0]) * 0.05f, 0.05f);
        }
        if (REPS > 1) bar_lds();   // protect ubuf reuse across reps
    }
}

extern "C" void kernel_launch(void* const* d_in, const int* in_sizes, int n_in,
                              void* d_out, int out_size, void* d_ws, size_t ws_size,
                              hipStream_t stream) {
    const float* node_feats = (const float*)d_in[0];
    const float* adj        = (const float*)d_in[1];
    const float* context    = (const float*)d_in[2];
    const float* base_preds = (const float*)d_in[3];
    const float* W1         = (const float*)d_in[4];
    const float* a1         = (const float*)d_in[5];
    const float* W2         = (const float*)d_in[6];
    const float* a2         = (const float*)d_in[7];
    const float* wh1_w = (const float*)d_in[8];
    const float* wh1_b = (const float*)d_in[9];
    const float* wh2_w = (const float*)d_in[10];
    const float* wh2_b = (const float*)d_in[11];
    const float* wh3_w = (const float*)d_in[12];
    const float* wh3_b = (const float*)d_in[13];
    const float* rh1_w = (const float*)d_in[14];
    const float* rh1_b = (const float*)d_in[15];
    const float* rh2_w = (const float*)d_in[16];
    const float* rh2_b = (const float*)d_in[17];
    float* out = (float*)d_out;

    char* ws = (char*)d_ws;
    us* W1b = (us*)ws;                // 131072 shorts
    us* W2b = W1b + 131072;           // 65536
    us* Whb = W2b + 65536;            // 98304 (wh1_w || rh1_w)
    float* scratch = (float*)(ws + (1 << 20));   // diag sink (6*B_SZ floats), ws >= 67MB

    pack_weights<<<288, 256, 0, stream>>>(W1, W2, wh1_w, rh1_w, W1b);

    // Diagnostic dispatch: no-attn body x2 reps -> scratch. (Measurement; see theory.)
    fused_all_t<false, 2><<<2048, 512, 0, stream>>>(node_feats, W1b, W2b, Whb, adj, a1, a2,
                                                    context, wh1_b, wh2_w, wh2_b, wh3_w, wh3_b,
                                                    rh1_b, rh2_w, rh2_b, base_preds, scratch);

    // Real dispatch: exact round-8 kernel (276us), writes out. Last -> correct output.
    fused_all_t<true, 1><<<2048, 512, 0, stream>>>(node_feats, W1b, W2b, Whb, adj, a1, a2,
                                                   context, wh1_b, wh2_w, wh2_b, wh3_w, wh3_b,
                                                   rh1_b, rh2_w, rh2_b, base_preds, out);
}

// Round 11
// 603.965 us; speedup vs baseline: 1.5901x; 1.5901x over previous
//
#include <hip/hip_runtime.h>

#define B_SZ 16384
#define NN 7
#define HID 256
#define COMB 2048

typedef __attribute__((ext_vector_type(8))) short short8;
typedef __attribute__((ext_vector_type(4))) float floatx4;
typedef __attribute__((ext_vector_type(4))) unsigned short ushortx4;
typedef unsigned short us;

__device__ __forceinline__ float bf2f(us u) {
    union { unsigned int i; float f; } v; v.i = ((unsigned int)u) << 16; return v.f;
}
__device__ __forceinline__ us f2bf(float f) {  // RNE
    union { unsigned int i; float f; } v; v.f = f;
    return (us)((v.i + 0x7FFFu + ((v.i >> 16) & 1u)) >> 16);
}
__device__ __forceinline__ us f2bf_fast(float f) {  // round-half-up (hot path)
    union { unsigned int i; float f; } v; v.f = f;
    return (us)((v.i + 0x8000u) >> 16);
}

// LDS-only barrier (round-8: neutral vs __syncthreads, avoids the full vmcnt drain).
__device__ __forceinline__ void bar_lds() {
    asm volatile("s_waitcnt lgkmcnt(0)" ::: "memory");
    __builtin_amdgcn_s_barrier();
}

// Swizzled chunk-major offsets (chunk = 8 bf16 = 16B); verified rounds 2/4-10.
// hs: 64 rows x 256 cols -> 2048 chunks (32KB).
__device__ __forceinline__ int hoff(int r, int k8) {
    return ((r >> 3) << 8) | ((r & 7) << 5) | (k8 & 24) | ((k8 ^ r) & 7);
}
// As: 64 rows x 64 cols -> 512 chunks per buffer.
__device__ __forceinline__ int aoff(int r, int k8) {
    return ((r >> 3) << 6) | ((r & 7) << 3) | ((k8 ^ r) & 7);
}

// Pack W1 (131072), W2 (65536), wh1_w (65536), rh1_w (32768) fp32 -> contiguous bf16 dst.
__global__ __launch_bounds__(256) void pack_weights(const float* __restrict__ W1,
                                                    const float* __restrict__ W2,
                                                    const float* __restrict__ wh1,
                                                    const float* __restrict__ rh1,
                                                    us* __restrict__ dst) {
    int i = (blockIdx.x * 256 + threadIdx.x) * 4;
    if (i >= 294912) return;
    const float* src; int off;
    if (i < 131072)      { src = W1;  off = i; }
    else if (i < 196608) { src = W2;  off = i - 131072; }
    else if (i < 262144) { src = wh1; off = i - 196608; }
    else                 { src = rh1; off = i - 262144; }
    floatx4 v = *(const floatx4*)(src + off);
    ushortx4 o = {f2bf(v[0]), f2bf(v[1]), f2bf(v[2]), f2bf(v[3])};
    *(ushortx4*)(dst + i) = o;
}

// GAT attention for ONE graph by one wave, in-place in swizzled hs (round-2 verified).
// Ablation (round 10): both attn calls together cost only ~29us of the 276us — keep as is.
template <bool WRITE_ALPHA>
__device__ __forceinline__ void attn_graph(us* hs, int r0, const float* adjs, const float* avec,
                                           float* alpha_dst, int lane) {
    const int k8 = lane >> 1, sub = (lane & 1) * 4;   // lane owns cols lane*4..lane*4+3
    float hv[NN][4];
#pragma unroll
    for (int n = 0; n < NN; ++n) {
        ushortx4 rr = *(const ushortx4*)(hs + hoff(r0 + n, k8) * 8 + sub);
        hv[n][0] = bf2f(rr[0]); hv[n][1] = bf2f(rr[1]);
        hv[n][2] = bf2f(rr[2]); hv[n][3] = bf2f(rr[3]);
    }
    floatx4 ai = *(const floatx4*)(avec + lane * 4);
    floatx4 aj = *(const floatx4*)(avec + HID + lane * 4);
    float si[NN], sj[NN];
#pragma unroll
    for (int n = 0; n < NN; ++n) {
        float pi = hv[n][0] * ai[0] + hv[n][1] * ai[1] + hv[n][2] * ai[2] + hv[n][3] * ai[3];
        float pj = hv[n][0] * aj[0] + hv[n][1] * aj[1] + hv[n][2] * aj[2] + hv[n][3] * aj[3];
#pragma unroll
        for (int off = 32; off; off >>= 1) {
            pi += __shfl_xor(pi, off);
            pj += __shfl_xor(pj, off);
        }
        si[n] = pi; sj[n] = pj;
    }
    const int j = lane & 7;
    float sjm = sj[0];
    if (j == 1) sjm = sj[1];
    if (j == 2) sjm = sj[2];
    if (j == 3) sjm = sj[3];
    if (j == 4) sjm = sj[4];
    if (j == 5) sjm = sj[5];
    if (j == 6) sjm = sj[6];
    const int jc = (j < 7) ? j : 0;
    float alpha[NN];
#pragma unroll
    for (int i = 0; i < NN; ++i) {
        float x = si[i] + sjm;
        x = (x >= 0.f) ? x : 0.2f * x;                     // leaky_relu 0.2
        bool ok = (j < 7) && (adjs[i * 7 + jc] != 0.f);    // adj mask + dummy col
        float e = ok ? x : -1e30f;
        float m = e;
        m = fmaxf(m, __shfl_xor(m, 1, 8));
        m = fmaxf(m, __shfl_xor(m, 2, 8));
        m = fmaxf(m, __shfl_xor(m, 4, 8));
        float ex = ok ? __expf(e - m) : 0.f;
        float s = ex;
        s += __shfl_xor(s, 1, 8);
        s += __shfl_xor(s, 2, 8);
        s += __shfl_xor(s, 4, 8);
        alpha[i] = (s > 0.f) ? ex * __frcp_rn(s) : 0.f;    // nan_to_num path
    }
    if (WRITE_ALPHA && lane < 7) {
#pragma unroll
        for (int i = 0; i < NN; ++i) alpha_dst[i * NN + lane] = alpha[i];
    }
#pragma unroll
    for (int i = 0; i < NN; ++i) {
        floatx4 o = (floatx4){0.f, 0.f, 0.f, 0.f};
#pragma unroll
        for (int jj = 0; jj < NN; ++jj) {
            float a = __shfl(alpha[i], jj, 8);
            o[0] += a * hv[jj][0]; o[1] += a * hv[jj][1];
            o[2] += a * hv[jj][2]; o[3] += a * hv[jj][3];
        }
        ushortx4 st = {f2bf(fmaxf(o[0], 0.f)), f2bf(fmaxf(o[1], 0.f)),
                       f2bf(fmaxf(o[2], 0.f)), f2bf(fmaxf(o[3], 0.f))};
        *(ushortx4*)(hs + hoff(r0 + i, k8) * 8 + sub) = st;   // relu
    }
}

// C-tile writeback (rows<56) into swizzled hs. col = wave*32 + ct*16 + m16.
__device__ __forceinline__ void cwrite(us* hs, floatx4 (&acc)[4][2], int wave, int quad, int m16) {
#pragma unroll
    for (int rt = 0; rt < 4; ++rt)
#pragma unroll
        for (int ct = 0; ct < 2; ++ct)
#pragma unroll
            for (int i = 0; i < 4; ++i) {
                int row = rt * 16 + quad * 4 + i;
                if (row < 56)
                    hs[hoff(row, wave * 4 + ct * 2 + (m16 >> 3)) * 8 + (m16 & 7)] =
                        f2bf(acc[rt][ct][i]);
            }
}

// ---------------- Single fused kernel: GEMM1+attn1+GEMM2+attn2+head+finalize ----------------
// EXACT round-8 structure (276us). ONE change: __launch_bounds__(512,3) (was 4).
// Rationale (r10 ablation): non-attn machinery = 247/276us; diag spilled ~150B/thread
// (WRITE 300MB) — at (512,4) the allocator splits the unified file 64 VGPR/64 AGPR
// (VGPR_Count=64 every round) and the arch side spills. ~37 serial scratch reloads/thread
// x ~250cy at phase entries matches the unexplained stall. Cap 170 (512/3) gives the
// allocator slack to hold everything; r1->r2 (cap 84->128: spill 262->65MB, 328->276us)
// is the only lever with a consistent sign all session — extend it.
__global__ __launch_bounds__(512, 3) void fused_all(
    const float* __restrict__ Af, const us* __restrict__ W1b, const us* __restrict__ W2b,
    const us* __restrict__ Whb, const float* __restrict__ adj, const float* __restrict__ a1v,
    const float* __restrict__ a2v, const float* __restrict__ context,
    const float* __restrict__ wh1_b, const float* __restrict__ wh2_w,
    const float* __restrict__ wh2_b, const float* __restrict__ wh3_w,
    const float* __restrict__ wh3_b, const float* __restrict__ rh1_b,
    const float* __restrict__ rh2_w, const float* __restrict__ rh2_b,
    const float* __restrict__ base_preds, float* __restrict__ out) {
    __shared__ __attribute__((aligned(16))) us hs[16384];     // 64r x 256c swizzled chunks
    __shared__ __attribute__((aligned(16))) char ubuf[16384]; // As dbuf | red(12288B)+fin
    __shared__ float adjs[52];
    us* As = (us*)ubuf;
    float* red = (float*)ubuf;
    float* fin = red + 3072;
    const int tid = threadIdx.x;
    const int wave = tid >> 6, lane = tid & 63;
    const int quad = lane >> 4, m16 = lane & 15;
    const long gbase = (long)blockIdx.x * 8;
    if (tid < 49) adjs[tid] = adj[tid];
    // zero pad rows 56..63: padded MFMA A-rows read clean zeros
    *(ushortx4*)(hs + 14336 + tid * 4) = (ushortx4){0, 0, 0, 0};

    floatx4 acc[4][2];
#pragma unroll
    for (int rt = 0; rt < 4; ++rt)
#pragma unroll
        for (int ct = 0; ct < 2; ++ct) acc[rt][ct] = (floatx4){0.f, 0.f, 0.f, 0.f};

    // ---- GEMM1: h1(56x256) = node_feats(56x512) @ W1^T, dbuf LDS staging ----
    const int r = tid >> 3, kq8 = tid & 7;
    long rowA = gbase * 7 + r; if (rowA > 114687) rowA = 114687;   // pad-row clamp
    const float* aptr = Af + rowA * 512 + kq8 * 8;
    us* wdst = As + aoff(r, kq8) * 8;
    const int colb = wave * 32;

    floatx4 v0 = *(const floatx4*)aptr;
    floatx4 v1 = *(const floatx4*)(aptr + 4);
#pragma unroll
    for (int s = 0; s < 8; ++s) {
        short8 sv;
        sv[0] = f2bf_fast(v0[0]); sv[1] = f2bf_fast(v0[1]);
        sv[2] = f2bf_fast(v0[2]); sv[3] = f2bf_fast(v0[3]);
        sv[4] = f2bf_fast(v1[0]); sv[5] = f2bf_fast(v1[1]);
        sv[6] = f2bf_fast(v1[2]); sv[7] = f2bf_fast(v1[3]);
        if (s < 7) {   // prefetch next stage; stays in flight across bar_lds
            v0 = *(const floatx4*)(aptr + (s + 1) * 64);
            v1 = *(const floatx4*)(aptr + (s + 1) * 64 + 4);
        }
        *(short8*)(wdst + (s & 1) * 4096) = sv;
        bar_lds();                             // single LDS-only barrier/stage (dbuf)
        const us* Ab = As + (s & 1) * 4096;
        const int k0 = s * 64;
#pragma unroll
        for (int t = 0; t < 2; ++t) {
            short8 b0 = *(const short8*)(W1b + (long)(colb + m16) * 512 + k0 + t * 32 + quad * 8);
            short8 b1 = *(const short8*)(W1b + (long)(colb + 16 + m16) * 512 + k0 + t * 32 + quad * 8);
            short8 a[4];
#pragma unroll
            for (int rt = 0; rt < 4; ++rt)
                a[rt] = *(const short8*)(Ab + aoff(rt * 16 + m16, t * 4 + quad) * 8);
#pragma unroll
            for (int rt = 0; rt < 4; ++rt) {
                acc[rt][0] = __builtin_amdgcn_mfma_f32_16x16x32_bf16(a[rt], b0, acc[rt][0], 0, 0, 0);
                acc[rt][1] = __builtin_amdgcn_mfma_f32_16x16x32_bf16(a[rt], b1, acc[rt][1], 0, 0, 0);
            }
        }
    }
    cwrite(hs, acc, wave, quad, m16);          // h1 pre-relu -> hs
    bar_lds();
    attn_graph<false>(hs, wave * NN, adjs, a1v, nullptr, lane);   // x2 in place
    bar_lds();

    // ---- GEMM2: h2 = x2(56x256) @ W2^T — A straight from hs, no staging ----
#pragma unroll
    for (int rt = 0; rt < 4; ++rt)
#pragma unroll
        for (int ct = 0; ct < 2; ++ct) acc[rt][ct] = (floatx4){0.f, 0.f, 0.f, 0.f};
#pragma unroll
    for (int s = 0; s < 4; ++s) {
        const int k0 = s * 64;
#pragma unroll
        for (int t = 0; t < 2; ++t) {
            short8 b0 = *(const short8*)(W2b + (long)(colb + m16) * 256 + k0 + t * 32 + quad * 8);
            short8 b1 = *(const short8*)(W2b + (long)(colb + 16 + m16) * 256 + k0 + t * 32 + quad * 8);
            short8 a[4];
#pragma unroll
            for (int rt = 0; rt < 4; ++rt)
                a[rt] = *(const short8*)(hs + hoff(rt * 16 + m16, s * 8 + t * 4 + quad) * 8);
#pragma unroll
            for (int rt = 0; rt < 4; ++rt) {
                acc[rt][0] = __builtin_amdgcn_mfma_f32_16x16x32_bf16(a[rt], b0, acc[rt][0], 0, 0, 0);
                acc[rt][1] = __builtin_amdgcn_mfma_f32_16x16x32_bf16(a[rt], b1, acc[rt][1], 0, 0, 0);
            }
        }
    }
    bar_lds();                                 // all hs reads done before in-place overwrite
    cwrite(hs, acc, wave, quad, m16);          // h2 pre-relu -> hs
    bar_lds();
    attn_graph<true>(hs, wave * NN, adjs, a2v, out + 6 * B_SZ + (gbase + wave) * 49, lane);
    bar_lds();

    // ---- head GEMM: 8 graphs x 48 outs, K=2048 split over waves (wave 7 = context) ----
    floatx4 acc3[3];
#pragma unroll
    for (int ct = 0; ct < 3; ++ct) acc3[ct] = (floatx4){0.f, 0.f, 0.f, 0.f};
    const int g = m16 & 7;
#pragma unroll
    for (int s2 = 0; s2 < 8; ++s2) {
        const int kk = s2 * 32;
        short8 a;
        if (wave < 7) {
            a = *(const short8*)(hs + hoff(g * NN + wave, s2 * 4 + quad) * 8);
        } else {
            const float* cp = context + (gbase + g) * 256 + kk + quad * 8;
            floatx4 c0 = *(const floatx4*)cp;
            floatx4 c1 = *(const floatx4*)(cp + 4);
            a[0] = (short)f2bf(c0[0]); a[1] = (short)f2bf(c0[1]);
            a[2] = (short)f2bf(c0[2]); a[3] = (short)f2bf(c0[3]);
            a[4] = (short)f2bf(c1[0]); a[5] = (short)f2bf(c1[1]);
            a[6] = (short)f2bf(c1[2]); a[7] = (short)f2bf(c1[3]);
        }
#pragma unroll
        for (int ct = 0; ct < 3; ++ct) {
            short8 bh = *(const short8*)(Whb + (long)(ct * 16 + m16) * COMB + wave * 256 + kk + quad * 8);
            acc3[ct] = __builtin_amdgcn_mfma_f32_16x16x32_bf16(a, bh, acc3[ct], 0, 0, 0);
        }
    }
#pragma unroll
    for (int ct = 0; ct < 3; ++ct)
#pragma unroll
        for (int i = 0; i < 4; ++i) {
            int g2 = quad * 4 + i;             // C row = graph
            if (g2 < 8) red[wave * 384 + g2 * 48 + ct * 16 + m16] = acc3[ct][i];
        }
    bar_lds();
    if (tid < 384) {
        float ssum = 0.f;
#pragma unroll
        for (int w = 0; w < 8; ++w) ssum += red[w * 384 + tid];
        fin[tid] = ssum;
    }
    bar_lds();

    // ---- finalize: wave-parallel, 8 lanes per graph (tid<64, wave 0) ----
    const int fj = lane & 7, fg = lane >> 3;
    const long fb = gbase + fg;
    float rp = 0.f;
    float* t1s = red;            // reuse (red dead): 8*32
    float* t2s = red + 256;      // 8*16
    if (tid < 64) {
        const float* g48 = fin + fg * 48;
#pragma unroll
        for (int x = 0; x < 4; ++x) {
            int k = fj * 4 + x;
            t1s[fg * 32 + k] = fmaxf(g48[k] + wh1_b[k], 0.f);
        }
#pragma unroll
        for (int x = 0; x < 2; ++x) {
            int k = fj * 2 + x;
            float rv = tanhf(g48[32 + k] + rh1_b[k]);
            rp += rh2_w[k] * rv;
        }
    }
    bar_lds();
    if (tid < 64) {
        float s0 = wh2_b[fj * 2], s1 = wh2_b[fj * 2 + 1];
#pragma unroll
        for (int k = 0; k < 32; ++k) {
            float tv = t1s[fg * 32 + k];
            s0 += wh2_w[(fj * 2) * 32 + k] * tv;
            s1 += wh2_w[(fj * 2 + 1) * 32 + k] * tv;
        }
        t2s[fg * 16 + fj * 2] = fmaxf(s0, 0.f);
        t2s[fg * 16 + fj * 2 + 1] = fmaxf(s1, 0.f);
    }
    bar_lds();
    if (tid < 64) {
        float rw = -1e30f;
        if (fj < 5) {
            float s = wh3_b[fj];
#pragma unroll
            for (int k = 0; k < 16; ++k) s += wh3_w[fj * 16 + k] * t2s[fg * 16 + k];
            rw = s;
        }
        float m = rw;
        m = fmaxf(m, __shfl_xor(m, 1, 8));
        m = fmaxf(m, __shfl_xor(m, 2, 8));
        m = fmaxf(m, __shfl_xor(m, 4, 8));
        float e = (fj < 5) ? __expf(rw - m) : 0.f;
        float se = e;
        se += __shfl_xor(se, 1, 8);
        se += __shfl_xor(se, 2, 8);
        se += __shfl_xor(se, 4, 8);
        float inv = 1.f / se;
        float wp = 0.f;
        if (fj < 5) {
            float w = e * inv;
            out[B_SZ + fb * 5 + fj] = w;
            wp = w * base_preds[fb * 5 + fj];
        }
        wp += __shfl_xor(wp, 1, 8);
        wp += __shfl_xor(wp, 2, 8);
        wp += __shfl_xor(wp, 4, 8);
        float rs = rp;
        rs += __shfl_xor(rs, 1, 8);
        rs += __shfl_xor(rs, 2, 8);
        rs += __shfl_xor(rs, 4, 8);
        if (fj == 0) out[fb] = fmaxf(wp + (rs + rh2_b[0]) * 0.05f, 0.05f);
    }
}

extern "C" void kernel_launch(void* const* d_in, const int* in_sizes, int n_in,
                              void* d_out, int out_size, void* d_ws, size_t ws_size,
                              hipStream_t stream) {
    const float* node_feats = (const float*)d_in[0];
    const float* adj        = (const float*)d_in[1];
    const float* context    = (const float*)d_in[2];
    const float* base_preds = (const float*)d_in[3];
    const float* W1         = (const float*)d_in[4];
    const float* a1         = (const float*)d_in[5];
    const float* W2         = (const float*)d_in[6];
    const float* a2         = (const float*)d_in[7];
    const float* wh1_w = (const float*)d_in[8];
    const float* wh1_b = (const float*)d_in[9];
    const float* wh2_w = (const float*)d_in[10];
    const float* wh2_b = (const float*)d_in[11];
    const float* wh3_w = (const float*)d_in[12];
    const float* wh3_b = (const float*)d_in[13];
    const float* rh1_w = (const float*)d_in[14];
    const float* rh1_b = (const float*)d_in[15];
    const float* rh2_w = (const float*)d_in[16];
    const float* rh2_b = (const float*)d_in[17];
    float* out = (float*)d_out;

    char* ws = (char*)d_ws;
    us* W1b = (us*)ws;                // 131072 shorts
    us* W2b = W1b + 131072;           // 65536
    us* Whb = W2b + 65536;            // 98304 (wh1_w || rh1_w)

    pack_weights<<<288, 256, 0, stream>>>(W1, W2, wh1_w, rh1_w, W1b);

    fused_all<<<2048, 512, 0, stream>>>(node_feats, W1b, W2b, Whb, adj, a1, a2, context,
                                        wh1_b, wh2_w, wh2_b, wh3_w, wh3_b,
                                        rh1_b, rh2_w, rh2_b, base_preds, out);
}

// Round 12
// 514.028 us; speedup vs baseline: 1.8683x; 1.1750x over previous
//
#include <hip/hip_runtime.h>

#define B_SZ 16384
#define NN 7
#define HID 256
#define COMB 2048

typedef __attribute__((ext_vector_type(8))) short short8;
typedef __attribute__((ext_vector_type(4))) float floatx4;
typedef __attribute__((ext_vector_type(4))) unsigned short ushortx4;
typedef unsigned short us;

__device__ __forceinline__ float bf2f(us u) {
    union { unsigned int i; float f; } v; v.i = ((unsigned int)u) << 16; return v.f;
}
__device__ __forceinline__ us f2bf(float f) {  // RNE
    union { unsigned int i; float f; } v; v.f = f;
    return (us)((v.i + 0x7FFFu + ((v.i >> 16) & 1u)) >> 16);
}
__device__ __forceinline__ us f2bf_fast(float f) {  // round-half-up (hot path)
    union { unsigned int i; float f; } v; v.f = f;
    return (us)((v.i + 0x8000u) >> 16);
}

// LDS-only barrier (round-8: neutral vs __syncthreads, avoids the full vmcnt drain).
__device__ __forceinline__ void bar_lds() {
    asm volatile("s_waitcnt lgkmcnt(0)" ::: "memory");
    __builtin_amdgcn_s_barrier();
}

// Swizzled chunk-major offsets (chunk = 8 bf16 = 16B); verified rounds 2/4-11.
// hs: 64 rows x 256 cols -> 2048 chunks (32KB).
__device__ __forceinline__ int hoff(int r, int k8) {
    return ((r >> 3) << 8) | ((r & 7) << 5) | (k8 & 24) | ((k8 ^ r) & 7);
}
// As: 64 rows x 64 cols -> 512 chunks per buffer.
__device__ __forceinline__ int aoff(int r, int k8) {
    return ((r >> 3) << 6) | ((r & 7) << 3) | ((k8 ^ r) & 7);
}

// Pack W1 (131072), W2 (65536), wh1_w (65536), rh1_w (32768) fp32 -> contiguous bf16 dst.
__global__ __launch_bounds__(256) void pack_weights(const float* __restrict__ W1,
                                                    const float* __restrict__ W2,
                                                    const float* __restrict__ wh1,
                                                    const float* __restrict__ rh1,
                                                    us* __restrict__ dst) {
    int i = (blockIdx.x * 256 + threadIdx.x) * 4;
    if (i >= 294912) return;
    const float* src; int off;
    if (i < 131072)      { src = W1;  off = i; }
    else if (i < 196608) { src = W2;  off = i - 131072; }
    else if (i < 262144) { src = wh1; off = i - 196608; }
    else                 { src = rh1; off = i - 262144; }
    floatx4 v = *(const floatx4*)(src + off);
    ushortx4 o = {f2bf(v[0]), f2bf(v[1]), f2bf(v[2]), f2bf(v[3])};
    *(ushortx4*)(dst + i) = o;
}

// GAT attention for ONE graph by one wave, in-place in swizzled hs (round-2 verified).
// Ablation (round 10): both attn calls together = ~29us of 276us — leave untouched.
template <bool WRITE_ALPHA>
__device__ __forceinline__ void attn_graph(us* hs, int r0, const float* adjs, const float* avec,
                                           float* alpha_dst, int lane) {
    const int k8 = lane >> 1, sub = (lane & 1) * 4;   // lane owns cols lane*4..lane*4+3
    float hv[NN][4];
#pragma unroll
    for (int n = 0; n < NN; ++n) {
        ushortx4 rr = *(const ushortx4*)(hs + hoff(r0 + n, k8) * 8 + sub);
        hv[n][0] = bf2f(rr[0]); hv[n][1] = bf2f(rr[1]);
        hv[n][2] = bf2f(rr[2]); hv[n][3] = bf2f(rr[3]);
    }
    floatx4 ai = *(const floatx4*)(avec + lane * 4);
    floatx4 aj = *(const floatx4*)(avec + HID + lane * 4);
    float si[NN], sj[NN];
#pragma unroll
    for (int n = 0; n < NN; ++n) {
        float pi = hv[n][0] * ai[0] + hv[n][1] * ai[1] + hv[n][2] * ai[2] + hv[n][3] * ai[3];
        float pj = hv[n][0] * aj[0] + hv[n][1] * aj[1] + hv[n][2] * aj[2] + hv[n][3] * aj[3];
#pragma unroll
        for (int off = 32; off; off >>= 1) {
            pi += __shfl_xor(pi, off);
            pj += __shfl_xor(pj, off);
        }
        si[n] = pi; sj[n] = pj;
    }
    const int j = lane & 7;
    float sjm = sj[0];
    if (j == 1) sjm = sj[1];
    if (j == 2) sjm = sj[2];
    if (j == 3) sjm = sj[3];
    if (j == 4) sjm = sj[4];
    if (j == 5) sjm = sj[5];
    if (j == 6) sjm = sj[6];
    const int jc = (j < 7) ? j : 0;
    float alpha[NN];
#pragma unroll
    for (int i = 0; i < NN; ++i) {
        float x = si[i] + sjm;
        x = (x >= 0.f) ? x : 0.2f * x;                     // leaky_relu 0.2
        bool ok = (j < 7) && (adjs[i * 7 + jc] != 0.f);    // adj mask + dummy col
        float e = ok ? x : -1e30f;
        float m = e;
        m = fmaxf(m, __shfl_xor(m, 1, 8));
        m = fmaxf(m, __shfl_xor(m, 2, 8));
        m = fmaxf(m, __shfl_xor(m, 4, 8));
        float ex = ok ? __expf(e - m) : 0.f;
        float s = ex;
        s += __shfl_xor(s, 1, 8);
        s += __shfl_xor(s, 2, 8);
        s += __shfl_xor(s, 4, 8);
        alpha[i] = (s > 0.f) ? ex * __frcp_rn(s) : 0.f;    // nan_to_num path
    }
    if (WRITE_ALPHA && lane < 7) {
#pragma unroll
        for (int i = 0; i < NN; ++i) alpha_dst[i * NN + lane] = alpha[i];
    }
#pragma unroll
    for (int i = 0; i < NN; ++i) {
        floatx4 o = (floatx4){0.f, 0.f, 0.f, 0.f};
#pragma unroll
        for (int jj = 0; jj < NN; ++jj) {
            float a = __shfl(alpha[i], jj, 8);
            o[0] += a * hv[jj][0]; o[1] += a * hv[jj][1];
            o[2] += a * hv[jj][2]; o[3] += a * hv[jj][3];
        }
        ushortx4 st = {f2bf(fmaxf(o[0], 0.f)), f2bf(fmaxf(o[1], 0.f)),
                       f2bf(fmaxf(o[2], 0.f)), f2bf(fmaxf(o[3], 0.f))};
        *(ushortx4*)(hs + hoff(r0 + i, k8) * 8 + sub) = st;   // relu
    }
}

// C-tile writeback (rows<56) into swizzled hs. col = wave*32 + ct*16 + m16.
__device__ __forceinline__ void cwrite(us* hs, floatx4 (&acc)[4][2], int wave, int quad, int m16) {
#pragma unroll
    for (int rt = 0; rt < 4; ++rt)
#pragma unroll
        for (int ct = 0; ct < 2; ++ct)
#pragma unroll
            for (int i = 0; i < 4; ++i) {
                int row = rt * 16 + quad * 4 + i;
                if (row < 56)
                    hs[hoff(row, wave * 4 + ct * 2 + (m16 >> 3)) * 8 + (m16 & 7)] =
                        f2bf(acc[rt][ct][i]);
            }
}

// ---------------- Single fused kernel: GEMM1+attn1+GEMM2+attn2+head+finalize ----------------
// EXACT round-8 structure (276us best) at (512,4). ONE mechanism change: the GEMM stage
// loops are ROLLED (#pragma unroll 1) and the A-fragment is loaded per-rt. Rationale
// (r10/r11): spill persists at every cap; the fully-unrolled stage loops let the scheduler
// hoist loads across stages -> peak arch-VGPR demand ~90-100 > the 64-reg half at (512,4)
// -> ~128 scratch round-trips/thread (64MB WRITE). Rolling bounds the scheduling window so
// peak fits 64 and spill dies WITHOUT losing the 2nd resident block (r11: trading a block
// for regs = -78us; this trades ILP the latency-bound kernel isn't using anyway).
__global__ __launch_bounds__(512, 4) void fused_all(
    const float* __restrict__ Af, const us* __restrict__ W1b, const us* __restrict__ W2b,
    const us* __restrict__ Whb, const float* __restrict__ adj, const float* __restrict__ a1v,
    const float* __restrict__ a2v, const float* __restrict__ context,
    const float* __restrict__ wh1_b, const float* __restrict__ wh2_w,
    const float* __restrict__ wh2_b, const float* __restrict__ wh3_w,
    const float* __restrict__ wh3_b, const float* __restrict__ rh1_b,
    const float* __restrict__ rh2_w, const float* __restrict__ rh2_b,
    const float* __restrict__ base_preds, float* __restrict__ out) {
    __shared__ __attribute__((aligned(16))) us hs[16384];     // 64r x 256c swizzled chunks
    __shared__ __attribute__((aligned(16))) char ubuf[16384]; // As dbuf | red(12288B)+fin
    __shared__ float adjs[52];
    us* As = (us*)ubuf;
    float* red = (float*)ubuf;
    float* fin = red + 3072;
    const int tid = threadIdx.x;
    const int wave = tid >> 6, lane = tid & 63;
    const int quad = lane >> 4, m16 = lane & 15;
    const long gbase = (long)blockIdx.x * 8;
    if (tid < 49) adjs[tid] = adj[tid];
    // zero pad rows 56..63: padded MFMA A-rows read clean zeros
    *(ushortx4*)(hs + 14336 + tid * 4) = (ushortx4){0, 0, 0, 0};

    floatx4 acc[4][2];
#pragma unroll
    for (int rt = 0; rt < 4; ++rt)
#pragma unroll
        for (int ct = 0; ct < 2; ++ct) acc[rt][ct] = (floatx4){0.f, 0.f, 0.f, 0.f};

    // ---- GEMM1: h1(56x256) = node_feats(56x512) @ W1^T, dbuf LDS staging, ROLLED ----
    const int r = tid >> 3, kq8 = tid & 7;
    long rowA = gbase * 7 + r; if (rowA > 114687) rowA = 114687;   // pad-row clamp
    const float* aptr = Af + rowA * 512 + kq8 * 8;
    us* wdst = As + aoff(r, kq8) * 8;
    const int colb = wave * 32;

    floatx4 v0 = *(const floatx4*)aptr;
    floatx4 v1 = *(const floatx4*)(aptr + 4);
#pragma unroll 1
    for (int s = 0; s < 8; ++s) {
        short8 sv;
        sv[0] = f2bf_fast(v0[0]); sv[1] = f2bf_fast(v0[1]);
        sv[2] = f2bf_fast(v0[2]); sv[3] = f2bf_fast(v0[3]);
        sv[4] = f2bf_fast(v1[0]); sv[5] = f2bf_fast(v1[1]);
        sv[6] = f2bf_fast(v1[2]); sv[7] = f2bf_fast(v1[3]);
        if (s < 7) {   // prefetch next stage; stays in flight across bar_lds
            v0 = *(const floatx4*)(aptr + (s + 1) * 64);
            v1 = *(const floatx4*)(aptr + (s + 1) * 64 + 4);
        }
        *(short8*)(wdst + (s & 1) * 4096) = sv;
        bar_lds();                             // single LDS-only barrier/stage (dbuf)
        const us* Ab = As + (s & 1) * 4096;
        const int k0 = s * 64;
#pragma unroll
        for (int t = 0; t < 2; ++t) {
            short8 b0 = *(const short8*)(W1b + (long)(colb + m16) * 512 + k0 + t * 32 + quad * 8);
            short8 b1 = *(const short8*)(W1b + (long)(colb + 16 + m16) * 512 + k0 + t * 32 + quad * 8);
#pragma unroll
            for (int rt = 0; rt < 4; ++rt) {   // per-rt A load: narrow live window
                short8 a = *(const short8*)(Ab + aoff(rt * 16 + m16, t * 4 + quad) * 8);
                acc[rt][0] = __builtin_amdgcn_mfma_f32_16x16x32_bf16(a, b0, acc[rt][0], 0, 0, 0);
                acc[rt][1] = __builtin_amdgcn_mfma_f32_16x16x32_bf16(a, b1, acc[rt][1], 0, 0, 0);
            }
        }
    }
    cwrite(hs, acc, wave, quad, m16);          // h1 pre-relu -> hs
    bar_lds();
    attn_graph<false>(hs, wave * NN, adjs, a1v, nullptr, lane);   // x2 in place
    bar_lds();

    // ---- GEMM2: h2 = x2(56x256) @ W2^T — A straight from hs, ROLLED s-loop ----
#pragma unroll
    for (int rt = 0; rt < 4; ++rt)
#pragma unroll
        for (int ct = 0; ct < 2; ++ct) acc[rt][ct] = (floatx4){0.f, 0.f, 0.f, 0.f};
#pragma unroll 1
    for (int s = 0; s < 4; ++s) {
        const int k0 = s * 64;
#pragma unroll
        for (int t = 0; t < 2; ++t) {
            short8 b0 = *(const short8*)(W2b + (long)(colb + m16) * 256 + k0 + t * 32 + quad * 8);
            short8 b1 = *(const short8*)(W2b + (long)(colb + 16 + m16) * 256 + k0 + t * 32 + quad * 8);
#pragma unroll
            for (int rt = 0; rt < 4; ++rt) {
                short8 a = *(const short8*)(hs + hoff(rt * 16 + m16, s * 8 + t * 4 + quad) * 8);
                acc[rt][0] = __builtin_amdgcn_mfma_f32_16x16x32_bf16(a, b0, acc[rt][0], 0, 0, 0);
                acc[rt][1] = __builtin_amdgcn_mfma_f32_16x16x32_bf16(a, b1, acc[rt][1], 0, 0, 0);
            }
        }
    }
    bar_lds();                                 // all hs reads done before in-place overwrite
    cwrite(hs, acc, wave, quad, m16);          // h2 pre-relu -> hs
    bar_lds();
    attn_graph<true>(hs, wave * NN, adjs, a2v, out + 6 * B_SZ + (gbase + wave) * 49, lane);
    bar_lds();

    // ---- head GEMM: 8 graphs x 48 outs, K=2048 split over waves (wave 7 = context) ----
    floatx4 acc3[3];
#pragma unroll
    for (int ct = 0; ct < 3; ++ct) acc3[ct] = (floatx4){0.f, 0.f, 0.f, 0.f};
    const int g = m16 & 7;
#pragma unroll 1
    for (int s2 = 0; s2 < 8; ++s2) {
        const int kk = s2 * 32;
        short8 a;
        if (wave < 7) {
            a = *(const short8*)(hs + hoff(g * NN + wave, s2 * 4 + quad) * 8);
        } else {
            const float* cp = context + (gbase + g) * 256 + kk + quad * 8;
            floatx4 c0 = *(const floatx4*)cp;
            floatx4 c1 = *(const floatx4*)(cp + 4);
            a[0] = (short)f2bf(c0[0]); a[1] = (short)f2bf(c0[1]);
            a[2] = (short)f2bf(c0[2]); a[3] = (short)f2bf(c0[3]);
            a[4] = (short)f2bf(c1[0]); a[5] = (short)f2bf(c1[1]);
            a[6] = (short)f2bf(c1[2]); a[7] = (short)f2bf(c1[3]);
        }
#pragma unroll
        for (int ct = 0; ct < 3; ++ct) {
            short8 bh = *(const short8*)(Whb + (long)(ct * 16 + m16) * COMB + wave * 256 + kk + quad * 8);
            acc3[ct] = __builtin_amdgcn_mfma_f32_16x16x32_bf16(a, bh, acc3[ct], 0, 0, 0);
        }
    }
#pragma unroll
    for (int ct = 0; ct < 3; ++ct)
#pragma unroll
        for (int i = 0; i < 4; ++i) {
            int g2 = quad * 4 + i;             // C row = graph
            if (g2 < 8) red[wave * 384 + g2 * 48 + ct * 16 + m16] = acc3[ct][i];
        }
    bar_lds();
    if (tid < 384) {
        float ssum = 0.f;
#pragma unroll
        for (int w = 0; w < 8; ++w) ssum += red[w * 384 + tid];
        fin[tid] = ssum;
    }
    bar_lds();

    // ---- finalize: wave-parallel, 8 lanes per graph (tid<64, wave 0) ----
    const int fj = lane & 7, fg = lane >> 3;
    const long fb = gbase + fg;
    float rp = 0.f;
    float* t1s = red;            // reuse (red dead): 8*32
    float* t2s = red + 256;      // 8*16
    if (tid < 64) {
        const float* g48 = fin + fg * 48;
#pragma unroll
        for (int x = 0; x < 4; ++x) {
            int k = fj * 4 + x;
            t1s[fg * 32 + k] = fmaxf(g48[k] + wh1_b[k], 0.f);
        }
#pragma unroll
        for (int x = 0; x < 2; ++x) {
            int k = fj * 2 + x;
            float rv = tanhf(g48[32 + k] + rh1_b[k]);
            rp += rh2_w[k] * rv;
        }
    }
    bar_lds();
    if (tid < 64) {
        float s0 = wh2_b[fj * 2], s1 = wh2_b[fj * 2 + 1];
#pragma unroll
        for (int k = 0; k < 32; ++k) {
            float tv = t1s[fg * 32 + k];
            s0 += wh2_w[(fj * 2) * 32 + k] * tv;
            s1 += wh2_w[(fj * 2 + 1) * 32 + k] * tv;
        }
        t2s[fg * 16 + fj * 2] = fmaxf(s0, 0.f);
        t2s[fg * 16 + fj * 2 + 1] = fmaxf(s1, 0.f);
    }
    bar_lds();
    if (tid < 64) {
        float rw = -1e30f;
        if (fj < 5) {
            float s = wh3_b[fj];
#pragma unroll
            for (int k = 0; k < 16; ++k) s += wh3_w[fj * 16 + k] * t2s[fg * 16 + k];
            rw = s;
        }
        float m = rw;
        m = fmaxf(m, __shfl_xor(m, 1, 8));
        m = fmaxf(m, __shfl_xor(m, 2, 8));
        m = fmaxf(m, __shfl_xor(m, 4, 8));
        float e = (fj < 5) ? __expf(rw - m) : 0.f;
        float se = e;
        se += __shfl_xor(se, 1, 8);
        se += __shfl_xor(se, 2, 8);
        se += __shfl_xor(se, 4, 8);
        float inv = 1.f / se;
        float wp = 0.f;
        if (fj < 5) {
            float w = e * inv;
            out[B_SZ + fb * 5 + fj] = w;
            wp = w * base_preds[fb * 5 + fj];
        }
        wp += __shfl_xor(wp, 1, 8);
        wp += __shfl_xor(wp, 2, 8);
        wp += __shfl_xor(wp, 4, 8);
        float rs = rp;
        rs += __shfl_xor(rs, 1, 8);
        rs += __shfl_xor(rs, 2, 8);
        rs += __shfl_xor(rs, 4, 8);
        if (fj == 0) out[fb] = fmaxf(wp + (rs + rh2_b[0]) * 0.05f, 0.05f);
    }
}

extern "C" void kernel_launch(void* const* d_in, const int* in_sizes, int n_in,
                              void* d_out, int out_size, void* d_ws, size_t ws_size,
                              hipStream_t stream) {
    const float* node_feats = (const float*)d_in[0];
    const float* adj        = (const float*)d_in[1];
    const float* context    = (const float*)d_in[2];
    const float* base_preds = (const float*)d_in[3];
    const float* W1         = (const float*)d_in[4];
    const float* a1         = (const float*)d_in[5];
    const float* W2         = (const float*)d_in[6];
    const float* a2         = (const float*)d_in[7];
    const float* wh1_w = (const float*)d_in[8];
    const float* wh1_b = (const float*)d_in[9];
    const float* wh2_w = (const float*)d_in[10];
    const float* wh2_b = (const float*)d_in[11];
    const float* wh3_w = (const float*)d_in[12];
    const float* wh3_b = (const float*)d_in[13];
    const float* rh1_w = (const float*)d_in[14];
    const float* rh1_b = (const float*)d_in[15];
    const float* rh2_w = (const float*)d_in[16];
    const float* rh2_b = (const float*)d_in[17];
    float* out = (float*)d_out;

    char* ws = (char*)d_ws;
    us* W1b = (us*)ws;                // 131072 shorts
    us* W2b = W1b + 131072;           // 65536
    us* Whb = W2b + 65536;            // 98304 (wh1_w || rh1_w)

    pack_weights<<<288, 256, 0, stream>>>(W1, W2, wh1_w, rh1_w, W1b);

    fused_all<<<2048, 512, 0, stream>>>(node_feats, W1b, W2b, Whb, adj, a1, a2, context,
                                        wh1_b, wh2_w, wh2_b, wh3_w, wh3_b,
                                        rh1_b, rh2_w, rh2_b, base_preds, out);
}